// Round 2
// baseline (118.752 us; speedup 1.0000x reference)
//
#include <hip/hip_runtime.h>
#include <hip/hip_bf16.h>

// Problem constants (B, NBC, H, W, HID, OUT = 4, 128, 64, 64, 64, 1)
// ALL tensors are float32 (reference uses jnp.float32 throughout).
#define BB   4
#define NBC  128
#define NINT 4096
#define HID  64

using short8  = __attribute__((ext_vector_type(8)))  short;  // 8 bf16 (4 VGPRs)
using float16 = __attribute__((ext_vector_type(16))) float;  // MFMA 32x32 acc

static __device__ __forceinline__ short f2bf(float f) {
    __hip_bfloat16 h = __float2bfloat16(f);
    return __builtin_bit_cast(short, h);
}

// ---------------------------------------------------------------------------
// Kernel 1: boundary encoder + a' = relu(relu(x@W0+b0)@W1+b1) @ G0w[:HID] + G0b
// one block (64 threads) per (b, bc) row; 512 blocks. Tiny (fp32 exact).
// ---------------------------------------------------------------------------
__global__ void __launch_bounds__(64) bge_prep(
    const float* __restrict__ binfo,  // (4,128,3)
    const float* __restrict__ W0,     // (3,64)
    const float* __restrict__ b0,     // (64)
    const float* __restrict__ W1,     // (64,64)
    const float* __restrict__ b1,     // (64)
    const float* __restrict__ G0w,    // (66,64)
    const float* __restrict__ G0b,    // (64)
    float* __restrict__ aprime)       // (4,128,64)
{
    const int row = blockIdx.x;   // b*128+bc
    const int t   = threadIdx.x;  // 0..63
    __shared__ float sh[HID];

    const float x0 = binfo[row*3+0];
    const float x1 = binfo[row*3+1];
    const float x2 = binfo[row*3+2];

    float h = x0*W0[t] + x1*W0[64+t] + x2*W0[128+t] + b0[t];
    h = fmaxf(h, 0.0f);
    sh[t] = h;
    __syncthreads();

    float acc = b1[t];
    #pragma unroll 8
    for (int k = 0; k < HID; ++k) acc += sh[k] * W1[k*64 + t];
    acc = fmaxf(acc, 0.0f);
    __syncthreads();
    sh[t] = acc;
    __syncthreads();

    float a = G0b[t];
    #pragma unroll 8
    for (int k = 0; k < HID; ++k) a += sh[k] * G0w[k*64 + t];
    aprime[row*HID + t] = a;
}

// ---------------------------------------------------------------------------
// Kernel 2: fused h1 build -> MFMA (h1 @ G1w) -> relu -> dot G2w -> mean(bc)
// grid (128, 4): blockIdx.x = interior tile of 32, blockIdx.y = batch.
// 4 waves/block; wave w handles bc in [32w, 32w+32).
// MFMA 32x32x16 bf16: A[m=lane&31][k=(lane>>5)*8+jj], B[k][n same mapping],
// C/D: col=lane&31, row=(reg&3)+8*(reg>>2)+4*(lane>>5)  [measured m74/m101].
// ---------------------------------------------------------------------------
__global__ void __launch_bounds__(256) bge_main(
    const float* __restrict__ icoord, // (4,4096,2)
    const float* __restrict__ G0w,    // (66,64)  rows 64,65 used here
    const float* __restrict__ G1w,    // (64,64)
    const float* __restrict__ G1b,    // (64)
    const float* __restrict__ G2w,    // (64,1)
    const float* __restrict__ G2b,    // (1)
    const float* __restrict__ aprime, // (4,128,64) fp32
    float* __restrict__ out)          // (4,4096)
{
    __shared__ float ldsA[NBC * HID];      // 32 KB: a' for this batch
    __shared__ float ldsS[4 * 64 * 16];    // 16 KB: per-lane partials
    __shared__ float red[32][8];

    const int b    = blockIdx.y;
    const int i0   = blockIdx.x * 32;
    const int tid  = threadIdx.x;
    const int wv   = tid >> 6;
    const int lane = tid & 63;
    const int hf   = lane >> 5;
    const int ln   = lane & 31;

    // stage a' (this batch) into LDS, coalesced float4
    {
        const float4* src = (const float4*)(aprime + (size_t)b * NBC * HID);
        float4* dst = (float4*)ldsA;
        for (int idx = tid; idx < NBC*HID/4; idx += 256) dst[idx] = src[idx];
    }

    // per-lane c values: c[i0+ln][k],  k = st*16 + hf*8 + jj
    const int i = i0 + ln;
    const float cx = icoord[((size_t)b*NINT + i)*2 + 0];
    const float cy = icoord[((size_t)b*NINT + i)*2 + 1];
    float cre[4][8];
    #pragma unroll
    for (int st = 0; st < 4; ++st)
        #pragma unroll
        for (int jj = 0; jj < 8; ++jj) {
            const int k = st*16 + hf*8 + jj;
            cre[st][jj] = cx*G0w[64*64 + k] + cy*G0w[65*64 + k];
        }

    // B fragments of G1w (fp32 -> bf16 once): k = st*16 + hf*8 + jj, n = t*32 + ln
    short8 bfrag[4][2];
    #pragma unroll
    for (int st = 0; st < 4; ++st)
        #pragma unroll
        for (int t = 0; t < 2; ++t)
            #pragma unroll
            for (int jj = 0; jj < 8; ++jj) {
                const int k = st*16 + hf*8 + jj;
                bfrag[st][t][jj] = f2bf(G1w[k*64 + t*32 + ln]);
            }

    const float b1v0 = G1b[ln],      b1v1 = G1b[32 + ln];
    const float g2v0 = G2w[ln],      g2v1 = G2w[32 + ln];
    const float g2bv = G2b[0];

    float16 bias0, bias1;   // G1b folded into MFMA C-operand of step 0
    #pragma unroll
    for (int r = 0; r < 16; ++r) { bias0[r] = b1v0; bias1[r] = b1v1; }

    float s[16];
    #pragma unroll
    for (int r = 0; r < 16; ++r) s[r] = 0.0f;

    __syncthreads();  // ldsA ready

    #pragma unroll 2
    for (int bc = wv*32; bc < wv*32 + 32; ++bc) {
        const float* arow = ldsA + bc*HID;
        float16 acc0, acc1;
        #pragma unroll
        for (int st = 0; st < 4; ++st) {
            const float* ap = arow + st*16 + hf*8;   // broadcast within half-wave
            short8 af;
            #pragma unroll
            for (int jj = 0; jj < 8; ++jj)
                af[jj] = f2bf(fmaxf(ap[jj] + cre[st][jj], 0.0f));
            if (st == 0) {
                acc0 = __builtin_amdgcn_mfma_f32_32x32x16_bf16(af, bfrag[0][0], bias0, 0, 0, 0);
                acc1 = __builtin_amdgcn_mfma_f32_32x32x16_bf16(af, bfrag[0][1], bias1, 0, 0, 0);
            } else {
                acc0 = __builtin_amdgcn_mfma_f32_32x32x16_bf16(af, bfrag[st][0], acc0, 0, 0, 0);
                acc1 = __builtin_amdgcn_mfma_f32_32x32x16_bf16(af, bfrag[st][1], acc1, 0, 0, 0);
            }
        }
        // epilogue: relu(h2) . G2w over this lane's 2 columns, accum over bc
        #pragma unroll
        for (int r = 0; r < 16; ++r)
            s[r] += fmaxf(acc0[r], 0.0f)*g2v0 + fmaxf(acc1[r], 0.0f)*g2v1;
    }

    // dump per-lane partials, reduce across waves and the 32 lanes of each half
    #pragma unroll
    for (int r = 0; r < 16; ++r) ldsS[(wv*64 + lane)*16 + r] = s[r];
    __syncthreads();

    // row m = (r&3) + 8*(r>>2) + 4*hf  ->  hf(m)=(m>>2)&1, r(m)=(m&3)|((m>>3)<<2)
    const int m   = tid >> 3;
    const int ch  = tid & 7;
    const int h_m = (m >> 2) & 1;
    const int r_m = (m & 3) | ((m >> 3) << 2);
    float acc = 0.0f;
    #pragma unroll
    for (int W = 0; W < 4; ++W)
        #pragma unroll
        for (int q = 0; q < 4; ++q) {
            const int l = h_m*32 + ch*4 + q;
            acc += ldsS[(W*64 + l)*16 + r_m];
        }
    red[m][ch] = acc;
    __syncthreads();

    if (tid < 32) {
        float tot = 0.0f;
        #pragma unroll
        for (int c2 = 0; c2 < 8; ++c2) tot += red[tid][c2];
        out[(size_t)b*NINT + i0 + tid] = tot * (1.0f/128.0f) + g2bv;
    }
}

// ---------------------------------------------------------------------------
extern "C" void kernel_launch(void* const* d_in, const int* in_sizes, int n_in,
                              void* d_out, int out_size, void* d_ws, size_t ws_size,
                              hipStream_t stream) {
    const float* binfo  = (const float*)d_in[0];
    const float* icoord = (const float*)d_in[1];
    const float* W0     = (const float*)d_in[2];
    const float* b0     = (const float*)d_in[3];
    const float* W1     = (const float*)d_in[4];
    const float* b1     = (const float*)d_in[5];
    const float* G0w    = (const float*)d_in[6];
    const float* G0b    = (const float*)d_in[7];
    const float* G1w    = (const float*)d_in[8];
    const float* G1b    = (const float*)d_in[9];
    const float* G2w    = (const float*)d_in[10];
    const float* G2b    = (const float*)d_in[11];

    float* aprime = (float*)d_ws;   // 4*128*64 fp32 = 128 KB scratch

    hipLaunchKernelGGL(bge_prep, dim3(BB*NBC), dim3(64), 0, stream,
                       binfo, W0, b0, W1, b1, G0w, G0b, aprime);
    hipLaunchKernelGGL(bge_main, dim3(NINT/32, BB), dim3(256), 0, stream,
                       icoord, G0w, G1w, G1b, G2w, G2b, aprime,
                       (float*)d_out);
}

// Round 4
// 117.772 us; speedup vs baseline: 1.0083x; 1.0083x over previous
//
#include <hip/hip_runtime.h>
#include <hip/hip_bf16.h>

// Problem constants (B, NBC, H, W, HID, OUT = 4, 128, 64, 64, 64, 1)
// ALL tensors are float32 (reference uses jnp.float32 throughout).
#define BB   4
#define NBC  128
#define NINT 4096
#define HID  64

using short8  = __attribute__((ext_vector_type(8)))  short;  // 8 bf16 (4 VGPRs)
using float16 = __attribute__((ext_vector_type(16))) float;  // MFMA 32x32 acc
using f2      = __attribute__((ext_vector_type(2)))  float;
using int4v   = __attribute__((ext_vector_type(4)))  int;

static __device__ __forceinline__ short f2bf(float f) {  // RNE, used once for G1w
    __hip_bfloat16 h = __float2bfloat16(f);
    return __builtin_bit_cast(short, h);
}
static __device__ __forceinline__ unsigned fbits(float f) {
    return __builtin_bit_cast(unsigned, f);
}
// pack trunc-bf16(lo), trunc-bf16(hi) into one dword: D = [hi31:16 | lo31:16]
static __device__ __forceinline__ unsigned pack_bf_trunc(float lo, float hi) {
    return __builtin_amdgcn_perm(fbits(hi), fbits(lo), 0x07060302u);
}

// ---------------------------------------------------------------------------
// Kernel 1: boundary encoder + a' = relu(relu(x@W0+b0)@W1+b1) @ G0w[:64] + G0b
// 128 blocks x 256 threads; wave w computes row blockIdx*4+w.
// W1 and G0w[:64] staged in LDS once per block (shared by 4 rows).
// ---------------------------------------------------------------------------
__global__ void __launch_bounds__(256) bge_prep(
    const float* __restrict__ binfo,  // (4,128,3)
    const float* __restrict__ W0,     // (3,64)
    const float* __restrict__ b0,     // (64)
    const float* __restrict__ W1,     // (64,64)
    const float* __restrict__ b1,     // (64)
    const float* __restrict__ G0w,    // (66,64)
    const float* __restrict__ G0b,    // (64)
    float* __restrict__ aprime)       // (4,128,64)
{
    __shared__ float sW1[HID * HID];   // 16 KB
    __shared__ float sG0[HID * HID];   // 16 KB
    __shared__ float shv [4][HID];
    __shared__ float shv2[4][HID];

    const int tid = threadIdx.x;
    const int wv  = tid >> 6;
    const int t   = tid & 63;
    const int row = blockIdx.x * 4 + wv;

    for (int idx = tid; idx < HID * HID / 4; idx += 256) {
        ((float4*)sW1)[idx] = ((const float4*)W1)[idx];
        ((float4*)sG0)[idx] = ((const float4*)G0w)[idx];
    }

    const float x0 = binfo[row*3+0];
    const float x1 = binfo[row*3+1];
    const float x2 = binfo[row*3+2];
    float h = fmaxf(x0*W0[t] + x1*W0[64+t] + x2*W0[128+t] + b0[t], 0.0f);
    shv[wv][t] = h;
    __syncthreads();                       // covers sW1/sG0 staging + shv

    float acc = b1[t];
    #pragma unroll 8
    for (int k = 0; k < HID; ++k) acc += shv[wv][k] * sW1[k*64 + t];
    shv2[wv][t] = fmaxf(acc, 0.0f);
    __syncthreads();

    float a = G0b[t];
    #pragma unroll 8
    for (int k = 0; k < HID; ++k) a += shv2[wv][k] * sG0[k*64 + t];
    aprime[row*HID + t] = a;
}

// ---------------------------------------------------------------------------
// Kernel 2: fused h1 build -> MFMA (h1 @ G1w) -> relu -> dot G2w -> mean(bc)
// grid (128, 4): blockIdx.x = interior tile of 32, blockIdx.y = batch.
// 512 threads = 8 waves; wave w handles bc in [16w, 16w+16).
// MFMA 32x32x16 bf16: A[m=lane&31][k=hf*8+jj(+16*st)], B same k-mapping,
// C/D: col=lane&31, row=(reg&3)+8*(reg>>2)+4*hf  [verified round 2].
// ---------------------------------------------------------------------------
__global__ void __launch_bounds__(512, 4) bge_main(
    const float* __restrict__ icoord, // (4,4096,2)
    const float* __restrict__ G0w,    // (66,64)  rows 64,65 used here
    const float* __restrict__ G1w,    // (64,64)
    const float* __restrict__ G1b,    // (64)
    const float* __restrict__ G2w,    // (64,1)
    const float* __restrict__ G2b,    // (1)
    const float* __restrict__ aprime, // (4,128,64) fp32
    float* __restrict__ out)          // (4,4096)
{
    // union: ldsA (8192 floats) reused as ldsS (8704) + red (512) after barrier
    __shared__ __align__(16) float smem[8704 + 512];   // 36 KB
    float* const ldsA = smem;
    float* const ldsS = smem;
    float* const red  = smem + 8704;

    const int b    = blockIdx.y;
    const int i0   = blockIdx.x * 32;
    const int tid  = threadIdx.x;
    const int wv   = tid >> 6;       // 0..7
    const int lane = tid & 63;
    const int hf   = lane >> 5;
    const int ln   = lane & 31;

    // stage a' (this batch, all 128 bc rows) into LDS, coalesced float4
    {
        const float4* src = (const float4*)(aprime + (size_t)b * NBC * HID);
        float4* dst = (float4*)ldsA;
        for (int idx = tid; idx < NBC*HID/4; idx += 512) dst[idx] = src[idx];
    }

    // per-lane c contribution: cre4[st][h] = float4 of cx*G0w[64][k]+cy*G0w[65][k]
    const int i = i0 + ln;
    const float cx = icoord[((size_t)b*NINT + i)*2 + 0];
    const float cy = icoord[((size_t)b*NINT + i)*2 + 1];
    float4 cre4[4][2];
    #pragma unroll
    for (int st = 0; st < 4; ++st)
        #pragma unroll
        for (int h = 0; h < 2; ++h) {
            const int k = st*16 + hf*8 + h*4;
            cre4[st][h] = make_float4(
                cx*G0w[64*64 + k+0] + cy*G0w[65*64 + k+0],
                cx*G0w[64*64 + k+1] + cy*G0w[65*64 + k+1],
                cx*G0w[64*64 + k+2] + cy*G0w[65*64 + k+2],
                cx*G0w[64*64 + k+3] + cy*G0w[65*64 + k+3]);
        }

    // B fragments of G1w (fp32 -> bf16 RNE, once): k = st*16+hf*8+jj, n = t*32+ln
    short8 bfrag[4][2];
    #pragma unroll
    for (int st = 0; st < 4; ++st)
        #pragma unroll
        for (int t = 0; t < 2; ++t)
            #pragma unroll
            for (int jj = 0; jj < 8; ++jj) {
                const int k = st*16 + hf*8 + jj;
                bfrag[st][t][jj] = f2bf(G1w[k*64 + t*32 + ln]);
            }

    const float b1v0 = G1b[ln],  b1v1 = G1b[32 + ln];
    const float g2v0 = G2w[ln],  g2v1 = G2w[32 + ln];
    const float g2bv = G2b[0];

    const float16 zc = (float16)0.0f;     // C operand; G1b added in epilogue
    f2 s2[8];
    #pragma unroll
    for (int q = 0; q < 8; ++q) s2[q] = (f2)0.0f;

    __syncthreads();  // ldsA ready

    #pragma unroll 2
    for (int bc = wv*16; bc < wv*16 + 16; ++bc) {
        const float* arow = ldsA + bc*HID;
        float16 acc0, acc1;
        #pragma unroll
        for (int st = 0; st < 4; ++st) {
            const float4* ap4 = (const float4*)(arow + st*16 + hf*8); // bcast/half
            float4 v0 = ap4[0], v1 = ap4[1];
            const float4 c0 = cre4[st][0], c1 = cre4[st][1];
            v0.x = fmaxf(v0.x + c0.x, 0.0f); v0.y = fmaxf(v0.y + c0.y, 0.0f);
            v0.z = fmaxf(v0.z + c0.z, 0.0f); v0.w = fmaxf(v0.w + c0.w, 0.0f);
            v1.x = fmaxf(v1.x + c1.x, 0.0f); v1.y = fmaxf(v1.y + c1.y, 0.0f);
            v1.z = fmaxf(v1.z + c1.z, 0.0f); v1.w = fmaxf(v1.w + c1.w, 0.0f);
            int4v di;
            di[0] = (int)pack_bf_trunc(v0.x, v0.y);
            di[1] = (int)pack_bf_trunc(v0.z, v0.w);
            di[2] = (int)pack_bf_trunc(v1.x, v1.y);
            di[3] = (int)pack_bf_trunc(v1.z, v1.w);
            const short8 af = __builtin_bit_cast(short8, di);
            if (st == 0) {
                acc0 = __builtin_amdgcn_mfma_f32_32x32x16_bf16(af, bfrag[0][0], zc, 0, 0, 0);
                acc1 = __builtin_amdgcn_mfma_f32_32x32x16_bf16(af, bfrag[0][1], zc, 0, 0, 0);
            } else {
                acc0 = __builtin_amdgcn_mfma_f32_32x32x16_bf16(af, bfrag[st][0], acc0, 0, 0, 0);
                acc1 = __builtin_amdgcn_mfma_f32_32x32x16_bf16(af, bfrag[st][1], acc1, 0, 0, 0);
            }
        }
        // epilogue: s += relu(h2 + G1b) . G2w  (packed pairs over reg index)
        #pragma unroll
        for (int q = 0; q < 8; ++q) {
            f2 a0; a0[0] = acc0[2*q] + b1v0; a0[1] = acc0[2*q+1] + b1v0;
            f2 a1; a1[0] = acc1[2*q] + b1v1; a1[1] = acc1[2*q+1] + b1v1;
            a0[0] = fmaxf(a0[0], 0.0f); a0[1] = fmaxf(a0[1], 0.0f);
            a1[0] = fmaxf(a1[0], 0.0f); a1[1] = fmaxf(a1[1], 0.0f);
            s2[q] += a0 * g2v0 + a1 * g2v1;
        }
    }

    __syncthreads();   // all waves done reading ldsA; reuse as ldsS

    {   // dump per-lane partials, stride 17 (odd -> conflict-free-ish)
        float* base = ldsS + (wv*64 + lane)*17;
        #pragma unroll
        for (int q = 0; q < 8; ++q) { base[2*q] = s2[q][0]; base[2*q+1] = s2[q][1]; }
    }
    __syncthreads();

    // reduce over 8 waves x 32 lanes for each of 32 rows m
    // row m = (r&3) + 8*(r>>2) + 4*hf  ->  hf(m)=(m>>2)&1, r(m)=(m&3)|((m>>3)<<2)
    {
        const int m   = tid >> 4;        // 0..31
        const int ch  = tid & 15;        // 16 threads per row
        const int h_m = (m >> 2) & 1;
        const int r_m = (m & 3) | ((m >> 3) << 2);
        const int wvr = ch >> 1;         // 0..7
        const int ln0 = (ch & 1) * 16;
        float acc = 0.0f;
        #pragma unroll
        for (int q = 0; q < 16; ++q)
            acc += ldsS[(wvr*64 + h_m*32 + ln0 + q)*17 + r_m];
        red[m*16 + ch] = acc;
    }
    __syncthreads();

    if (tid < 32) {
        float tot = 0.0f;
        #pragma unroll
        for (int c2 = 0; c2 < 16; ++c2) tot += red[tid*16 + c2];
        out[(size_t)b*NINT + i0 + tid] = tot * (1.0f/128.0f) + g2bv;
    }
}

// ---------------------------------------------------------------------------
extern "C" void kernel_launch(void* const* d_in, const int* in_sizes, int n_in,
                              void* d_out, int out_size, void* d_ws, size_t ws_size,
                              hipStream_t stream) {
    const float* binfo  = (const float*)d_in[0];
    const float* icoord = (const float*)d_in[1];
    const float* W0     = (const float*)d_in[2];
    const float* b0     = (const float*)d_in[3];
    const float* W1     = (const float*)d_in[4];
    const float* b1     = (const float*)d_in[5];
    const float* G0w    = (const float*)d_in[6];
    const float* G0b    = (const float*)d_in[7];
    const float* G1w    = (const float*)d_in[8];
    const float* G1b    = (const float*)d_in[9];
    const float* G2w    = (const float*)d_in[10];
    const float* G2b    = (const float*)d_in[11];

    float* aprime = (float*)d_ws;   // 4*128*64 fp32 = 128 KB scratch

    hipLaunchKernelGGL(bge_prep, dim3(BB*NBC/4), dim3(256), 0, stream,
                       binfo, W0, b0, W1, b1, G0w, G0b, aprime);
    hipLaunchKernelGGL(bge_main, dim3(NINT/32, BB), dim3(512), 0, stream,
                       icoord, G0w, G1w, G1b, G2w, G2b, aprime,
                       (float*)d_out);
}

// Round 5
// 115.290 us; speedup vs baseline: 1.0300x; 1.0215x over previous
//
#include <hip/hip_runtime.h>
#include <hip/hip_bf16.h>

// Problem constants (B, NBC, H, W, HID, OUT = 4, 128, 64, 64, 64, 1)
// ALL tensors are float32 (reference uses jnp.float32 throughout).
#define BB   4
#define NBC  128
#define NINT 4096
#define HID  64

using short8  = __attribute__((ext_vector_type(8)))  short;  // 8 bf16 (4 VGPRs)
using float16 = __attribute__((ext_vector_type(16))) float;  // MFMA 32x32 acc
using f2      = __attribute__((ext_vector_type(2)))  float;
using int4v   = __attribute__((ext_vector_type(4)))  int;

static __device__ __forceinline__ short f2bf(float f) {  // RNE, used once for G1w
    __hip_bfloat16 h = __float2bfloat16(f);
    return __builtin_bit_cast(short, h);
}
static __device__ __forceinline__ unsigned fbits(float f) {
    return __builtin_bit_cast(unsigned, f);
}
// pack trunc-bf16(lo), trunc-bf16(hi) into one dword: D = [hi31:16 | lo31:16]
static __device__ __forceinline__ unsigned pack_bf_trunc(float lo, float hi) {
    return __builtin_amdgcn_perm(fbits(hi), fbits(lo), 0x07060302u);
}

// ---------------------------------------------------------------------------
// Kernel 1: boundary encoder + a' = relu(relu(x@W0+b0)@W1+b1) @ G0w[:64] + G0b
// 128 blocks x 256 threads; wave w computes row blockIdx*4+w.
// W1 and G0w[:64] staged in LDS once per block (shared by 4 rows).
// ---------------------------------------------------------------------------
__global__ void __launch_bounds__(256) bge_prep(
    const float* __restrict__ binfo,  // (4,128,3)
    const float* __restrict__ W0,     // (3,64)
    const float* __restrict__ b0,     // (64)
    const float* __restrict__ W1,     // (64,64)
    const float* __restrict__ b1,     // (64)
    const float* __restrict__ G0w,    // (66,64)
    const float* __restrict__ G0b,    // (64)
    float* __restrict__ aprime)       // (4,128,64)
{
    __shared__ float sW1[HID * HID];   // 16 KB
    __shared__ float sG0[HID * HID];   // 16 KB
    __shared__ float shv [4][HID];
    __shared__ float shv2[4][HID];

    const int tid = threadIdx.x;
    const int wv  = tid >> 6;
    const int t   = tid & 63;
    const int row = blockIdx.x * 4 + wv;

    for (int idx = tid; idx < HID * HID / 4; idx += 256) {
        ((float4*)sW1)[idx] = ((const float4*)W1)[idx];
        ((float4*)sG0)[idx] = ((const float4*)G0w)[idx];
    }

    const float x0 = binfo[row*3+0];
    const float x1 = binfo[row*3+1];
    const float x2 = binfo[row*3+2];
    float h = fmaxf(x0*W0[t] + x1*W0[64+t] + x2*W0[128+t] + b0[t], 0.0f);
    shv[wv][t] = h;
    __syncthreads();                       // covers sW1/sG0 staging + shv

    float acc = b1[t];
    #pragma unroll 8
    for (int k = 0; k < HID; ++k) acc += shv[wv][k] * sW1[k*64 + t];
    shv2[wv][t] = fmaxf(acc, 0.0f);
    __syncthreads();

    float a = G0b[t];
    #pragma unroll 8
    for (int k = 0; k < HID; ++k) a += shv2[wv][k] * sG0[k*64 + t];
    aprime[row*HID + t] = a;
}

// ---------------------------------------------------------------------------
// Kernel 2: fused h1 build -> MFMA (h1 @ G1w) -> relu -> dot G2w -> mean(bc)
// grid (128, 4): blockIdx.x = interior tile of 32, blockIdx.y = batch.
// 512 threads = 8 waves; wave w handles bc in [16w, 16w+16).
// NOTE: no second __launch_bounds__ arg — R4 showed (512,4) caps VGPR at 64
// and spills acc/bfrag to scratch (WRITE_SIZE 64KB -> 16MB, dur flat 42us).
// MFMA 32x32x16 bf16: A[m=lane&31][k=hf*8+jj(+16*st)], B same k-mapping,
// C/D: col=lane&31, row=(reg&3)+8*(reg>>2)+4*hf  [verified round 2].
// ---------------------------------------------------------------------------
__global__ void __launch_bounds__(512) bge_main(
    const float* __restrict__ icoord, // (4,4096,2)
    const float* __restrict__ G0w,    // (66,64)  rows 64,65 used here
    const float* __restrict__ G1w,    // (64,64)
    const float* __restrict__ G1b,    // (64)
    const float* __restrict__ G2w,    // (64,1)
    const float* __restrict__ G2b,    // (1)
    const float* __restrict__ aprime, // (4,128,64) fp32
    float* __restrict__ out)          // (4,4096)
{
    // union: ldsA (8192 floats) reused as ldsS (8704) + red (512) after barrier
    __shared__ __align__(16) float smem[8704 + 512];   // 36 KB
    float* const ldsA = smem;
    float* const ldsS = smem;
    float* const red  = smem + 8704;

    const int b    = blockIdx.y;
    const int i0   = blockIdx.x * 32;
    const int tid  = threadIdx.x;
    const int wv   = tid >> 6;       // 0..7
    const int lane = tid & 63;
    const int hf   = lane >> 5;
    const int ln   = lane & 31;

    // stage a' (this batch, all 128 bc rows) into LDS, coalesced float4
    {
        const float4* src = (const float4*)(aprime + (size_t)b * NBC * HID);
        float4* dst = (float4*)ldsA;
        for (int idx = tid; idx < NBC*HID/4; idx += 512) dst[idx] = src[idx];
    }

    // per-lane c contribution: cre4[st][h] = float4 of cx*G0w[64][k]+cy*G0w[65][k]
    const int i = i0 + ln;
    const float cx = icoord[((size_t)b*NINT + i)*2 + 0];
    const float cy = icoord[((size_t)b*NINT + i)*2 + 1];
    float4 cre4[4][2];
    #pragma unroll
    for (int st = 0; st < 4; ++st)
        #pragma unroll
        for (int h = 0; h < 2; ++h) {
            const int k = st*16 + hf*8 + h*4;
            cre4[st][h] = make_float4(
                cx*G0w[64*64 + k+0] + cy*G0w[65*64 + k+0],
                cx*G0w[64*64 + k+1] + cy*G0w[65*64 + k+1],
                cx*G0w[64*64 + k+2] + cy*G0w[65*64 + k+2],
                cx*G0w[64*64 + k+3] + cy*G0w[65*64 + k+3]);
        }

    // B fragments of G1w (fp32 -> bf16 RNE, once): k = st*16+hf*8+jj, n = t*32+ln
    short8 bfrag[4][2];
    #pragma unroll
    for (int st = 0; st < 4; ++st)
        #pragma unroll
        for (int t = 0; t < 2; ++t)
            #pragma unroll
            for (int jj = 0; jj < 8; ++jj) {
                const int k = st*16 + hf*8 + jj;
                bfrag[st][t][jj] = f2bf(G1w[k*64 + t*32 + ln]);
            }

    const float b1v0 = G1b[ln],  b1v1 = G1b[32 + ln];
    const float g2v0 = G2w[ln],  g2v1 = G2w[32 + ln];
    const float g2bv = G2b[0];

    const float16 zc = (float16)0.0f;     // C operand; G1b added in epilogue
    f2 s2[8];
    #pragma unroll
    for (int q = 0; q < 8; ++q) s2[q] = (f2)0.0f;

    __syncthreads();  // ldsA ready

    #pragma unroll 2
    for (int bc = wv*16; bc < wv*16 + 16; ++bc) {
        const float* arow = ldsA + bc*HID;
        float16 acc0, acc1;
        #pragma unroll
        for (int st = 0; st < 4; ++st) {
            const float4* ap4 = (const float4*)(arow + st*16 + hf*8); // bcast/half
            float4 v0 = ap4[0], v1 = ap4[1];
            const float4 c0 = cre4[st][0], c1 = cre4[st][1];
            v0.x = fmaxf(v0.x + c0.x, 0.0f); v0.y = fmaxf(v0.y + c0.y, 0.0f);
            v0.z = fmaxf(v0.z + c0.z, 0.0f); v0.w = fmaxf(v0.w + c0.w, 0.0f);
            v1.x = fmaxf(v1.x + c1.x, 0.0f); v1.y = fmaxf(v1.y + c1.y, 0.0f);
            v1.z = fmaxf(v1.z + c1.z, 0.0f); v1.w = fmaxf(v1.w + c1.w, 0.0f);
            int4v di;
            di[0] = (int)pack_bf_trunc(v0.x, v0.y);
            di[1] = (int)pack_bf_trunc(v0.z, v0.w);
            di[2] = (int)pack_bf_trunc(v1.x, v1.y);
            di[3] = (int)pack_bf_trunc(v1.z, v1.w);
            const short8 af = __builtin_bit_cast(short8, di);
            if (st == 0) {
                acc0 = __builtin_amdgcn_mfma_f32_32x32x16_bf16(af, bfrag[0][0], zc, 0, 0, 0);
                acc1 = __builtin_amdgcn_mfma_f32_32x32x16_bf16(af, bfrag[0][1], zc, 0, 0, 0);
            } else {
                acc0 = __builtin_amdgcn_mfma_f32_32x32x16_bf16(af, bfrag[st][0], acc0, 0, 0, 0);
                acc1 = __builtin_amdgcn_mfma_f32_32x32x16_bf16(af, bfrag[st][1], acc1, 0, 0, 0);
            }
        }
        // epilogue: s += relu(h2 + G1b) . G2w  (packed pairs over reg index)
        #pragma unroll
        for (int q = 0; q < 8; ++q) {
            f2 a0; a0[0] = acc0[2*q] + b1v0; a0[1] = acc0[2*q+1] + b1v0;
            f2 a1; a1[0] = acc1[2*q] + b1v1; a1[1] = acc1[2*q+1] + b1v1;
            a0[0] = fmaxf(a0[0], 0.0f); a0[1] = fmaxf(a0[1], 0.0f);
            a1[0] = fmaxf(a1[0], 0.0f); a1[1] = fmaxf(a1[1], 0.0f);
            s2[q] += a0 * g2v0 + a1 * g2v1;
        }
    }

    __syncthreads();   // all waves done reading ldsA; reuse as ldsS

    {   // dump per-lane partials, stride 17 (odd -> conflict-free)
        float* base = ldsS + (wv*64 + lane)*17;
        #pragma unroll
        for (int q = 0; q < 8; ++q) { base[2*q] = s2[q][0]; base[2*q+1] = s2[q][1]; }
    }
    __syncthreads();

    // reduce over 8 waves x 32 lanes for each of 32 rows m
    // row m = (r&3) + 8*(r>>2) + 4*hf  ->  hf(m)=(m>>2)&1, r(m)=(m&3)|((m>>3)<<2)
    {
        const int m   = tid >> 4;        // 0..31
        const int ch  = tid & 15;        // 16 threads per row
        const int h_m = (m >> 2) & 1;
        const int r_m = (m & 3) | ((m >> 3) << 2);
        const int wvr = ch >> 1;         // 0..7
        const int ln0 = (ch & 1) * 16;
        float acc = 0.0f;
        #pragma unroll
        for (int q = 0; q < 16; ++q)
            acc += ldsS[(wvr*64 + h_m*32 + ln0 + q)*17 + r_m];
        red[m*16 + ch] = acc;
    }
    __syncthreads();

    if (tid < 32) {
        float tot = 0.0f;
        #pragma unroll
        for (int c2 = 0; c2 < 16; ++c2) tot += red[tid*16 + c2];
        out[(size_t)b*NINT + i0 + tid] = tot * (1.0f/128.0f) + g2bv;
    }
}

// ---------------------------------------------------------------------------
extern "C" void kernel_launch(void* const* d_in, const int* in_sizes, int n_in,
                              void* d_out, int out_size, void* d_ws, size_t ws_size,
                              hipStream_t stream) {
    const float* binfo  = (const float*)d_in[0];
    const float* icoord = (const float*)d_in[1];
    const float* W0     = (const float*)d_in[2];
    const float* b0     = (const float*)d_in[3];
    const float* W1     = (const float*)d_in[4];
    const float* b1     = (const float*)d_in[5];
    const float* G0w    = (const float*)d_in[6];
    const float* G0b    = (const float*)d_in[7];
    const float* G1w    = (const float*)d_in[8];
    const float* G1b    = (const float*)d_in[9];
    const float* G2w    = (const float*)d_in[10];
    const float* G2b    = (const float*)d_in[11];

    float* aprime = (float*)d_ws;   // 4*128*64 fp32 = 128 KB scratch

    hipLaunchKernelGGL(bge_prep, dim3(BB*NBC/4), dim3(256), 0, stream,
                       binfo, W0, b0, W1, b1, G0w, G0b, aprime);
    hipLaunchKernelGGL(bge_main, dim3(NINT/32, BB), dim3(512), 0, stream,
                       icoord, G0w, G1w, G1b, G2w, G2b, aprime,
                       (float*)d_out);
}